// Round 1
// baseline (302.418 us; speedup 1.0000x reference)
//
#include <hip/hip_runtime.h>

// WeightedBCELoss: out[b][s] = labels==0 ? -log(1-pred) : -weight[b]*log(pred)
// BATCH=4096, SENT=8192, all fp32 except labels (int32).
// Memory-bound elementwise: 12 B/elem, ~402 MB total -> ~64 us floor @ 6.3 TB/s.

#define WBCE_BATCH 4096
#define WBCE_SENT  8192
// float4 groups per row = SENT/4 = 2048 = 1<<11
#define LOG2_VEC_PER_ROW 11

__global__ __launch_bounds__(256) void WeightedBCELoss_70128226009669_kernel(
    const float4* __restrict__ pred4,
    const int4*  __restrict__ lab4,
    const float* __restrict__ weight,
    float4* __restrict__ out4)
{
    const int i = blockIdx.x * 256 + threadIdx.x;
    // Every wave covers indices within one row (2048 vec/row, multiple of 64),
    // so this load is wave-uniform -> scalar path.
    const int row = i >> LOG2_VEC_PER_ROW;
    const float w = weight[row];

    const float4 p = pred4[i];
    const int4  l = lab4[i];

    // Select the log argument first so we pay only ONE log per element.
    const float x0 = (l.x == 0) ? (1.0f - p.x) : p.x;
    const float x1 = (l.y == 0) ? (1.0f - p.y) : p.y;
    const float x2 = (l.z == 0) ? (1.0f - p.z) : p.z;
    const float x3 = (l.w == 0) ? (1.0f - p.w) : p.w;

    const float s0 = (l.x == 0) ? 1.0f : w;
    const float s1 = (l.y == 0) ? 1.0f : w;
    const float s2 = (l.z == 0) ? 1.0f : w;
    const float s3 = (l.w == 0) ? 1.0f : w;

    float4 o;
    o.x = -s0 * __logf(x0);
    o.y = -s1 * __logf(x1);
    o.z = -s2 * __logf(x2);
    o.w = -s3 * __logf(x3);

    out4[i] = o;
}

extern "C" void kernel_launch(void* const* d_in, const int* in_sizes, int n_in,
                              void* d_out, int out_size, void* d_ws, size_t ws_size,
                              hipStream_t stream) {
    const float4* pred4  = (const float4*)d_in[0];
    const int4*   lab4   = (const int4*)d_in[1];
    const float*  weight = (const float*)d_in[2];
    float4* out4 = (float4*)d_out;

    const int n_vec = (WBCE_BATCH * WBCE_SENT) / 4;  // 8,388,608
    const int block = 256;
    const int grid = n_vec / block;                  // 32,768 — exact, no tail

    WeightedBCELoss_70128226009669_kernel<<<grid, block, 0, stream>>>(
        pred4, lab4, weight, out4);
}